// Round 2
// baseline (114.871 us; speedup 1.0000x reference)
//
#include <hip/hip_runtime.h>

#define B_ 8
#define P_ 65536
#define G_ 32
#define C_ 2
#define K_ 5
#define T1_ 0.35f
#define T2_ 0.5f
#define ALPHA_ 0.25f
#define BETA_ 0.11f
#define V0_ 0.1f
#define V1_ 0.2f

// ---------------- workspace header (first 8192 bytes of d_ws, zeroed each call) ----
struct Hdr {
    double fl_n[B_], sl_n[B_], fl_c[B_], sl_c[B_];
    int npos[B_], npos_c[B_], csum[B_];
    int match_cnt[B_ * G_], c_match[B_ * G_], c_anchor_num[B_ * G_];
    float cut_v[B_ * G_];
    int cut_i[B_ * G_];
};
// big arrays appended at ws+8192: float best_score[B_*P_]; int best_idx[B_*P_];

// ---------------- helpers ----------------
__device__ __forceinline__ float iou_corner(float ax1, float ay1, float ax2, float ay2,
                                            float bx1, float by1, float bx2, float by2) {
    float lx = fmaxf(ax1, bx1), ly = fmaxf(ay1, by1);
    float rx = fminf(ax2, bx2), ry = fminf(ay2, by2);
    float w = fmaxf(rx - lx, 0.f), hh = fmaxf(ry - ly, 0.f);
    float inter = w * hh;
    float aa = (ax2 - ax1) * (ay2 - ay1);
    float ab = (bx2 - bx1) * (by2 - by1);
    return inter / (aa + ab - inter);
}

// decode(loc,prior) then IoU vs a gt box. contract(off) so kernels D and E
// produce BIT-IDENTICAL values (the stable-sort tie-break compares floats for
// equality across kernels).
__device__ __forceinline__ float decoded_iou(float4 pr, float4 lc,
                                             float tx1, float ty1, float tx2, float ty2) {
#pragma clang fp contract(off)
    float dcx = pr.x + lc.x * V0_ * pr.z;
    float dcy = pr.y + lc.y * V0_ * pr.w;
    float dw = pr.z * expf(lc.z * V1_);
    float dh = pr.w * expf(lc.w * V1_);
    float dx1 = dcx - dw * 0.5f, dy1 = dcy - dh * 0.5f;
    float dx2 = dcx + dw * 0.5f, dy2 = dcy + dh * 0.5f;
    float lx = fmaxf(tx1, dx1), ly = fmaxf(ty1, dy1);
    float rx = fminf(tx2, dx2), ry = fminf(ty2, dy2);
    float w = fmaxf(rx - lx, 0.f), hh = fmaxf(ry - ly, 0.f);
    float inter = w * hh;
    float aa = (tx2 - tx1) * (ty2 - ty1);
    float ab = (dx2 - dx1) * (dy2 - dy1);
    return inter / (aa + ab - inter);
}

__device__ __forceinline__ float focal_f(float t, float x, float fiou) {
    float ce = fmaxf(x, 0.f) - x * t + log1pf(expf(-fabsf(x)));
    float a = (t * ALPHA_ + (1.f - t) * (1.f - ALPHA_)) * fiou;
    float pt = (t == 1.0f) ? x : 1.f - x;
    float om = 1.f - pt;
    return a * om * om * ce;  // GAMMA = 2
}

__device__ __forceinline__ float sml1(float p, float t) {
    float x = fabsf(p - t);
    return (x >= BETA_) ? (x - 0.5f * BETA_) : (0.5f * x * x / BETA_);
}

// ---------------- kernels ----------------
__global__ void kInit(int* hw) {
    for (int k = threadIdx.x; k < 2048; k += 256) hw[k] = 0;  // zero first 8192 B
}

// A: prior<->gt IoU, best match per anchor, match_cnt histogram
__global__ __launch_bounds__(256) void kA(const float* __restrict__ priors,
                                          const float* __restrict__ targets, Hdr* h,
                                          float* __restrict__ best_score,
                                          int* __restrict__ best_idx) {
    int tid = threadIdx.x;
    int p = blockIdx.x * 256 + tid, b = blockIdx.y;
    __shared__ float tr[G_ * 5];
    __shared__ int hist[G_];
    if (tid < G_ * 5) tr[tid] = targets[b * G_ * 5 + tid];
    if (tid < G_) hist[tid] = 0;
    __syncthreads();
    float4 pr = ((const float4*)priors)[p];
    float px1 = pr.x - pr.z * 0.5f, py1 = pr.y - pr.w * 0.5f;
    float px2 = pr.x + pr.z * 0.5f, py2 = pr.y + pr.w * 0.5f;
    float best = -INFINITY;
    int bi = 0;
    for (int g = 0; g < G_; ++g) {
        float v = iou_corner(tr[g * 5], tr[g * 5 + 1], tr[g * 5 + 2], tr[g * 5 + 3],
                             px1, py1, px2, py2);
        if (v > best) { best = v; bi = g; }  // first-max == jnp.argmax
    }
    best_score[b * P_ + p] = best;
    best_idx[b * P_ + p] = bi;
    if (best > T1_) atomicAdd(&hist[bi], 1);
    __syncthreads();
    if (tid < G_ && hist[tid]) atomicAdd(&h->match_cnt[b * G_ + tid], hist[tid]);
}

// B: decode, c_iou over g, ignore/neg masks, normal focal+smoothL1, c_match
__global__ __launch_bounds__(256) void kB(const float* __restrict__ loc,
                                          const float* __restrict__ conf,
                                          const float* __restrict__ priors,
                                          const float* __restrict__ targets, Hdr* h,
                                          const float* __restrict__ best_score,
                                          const int* __restrict__ best_idx) {
    int tid = threadIdx.x;
    int p = blockIdx.x * 256 + tid, b = blockIdx.y;
    __shared__ float tr[G_ * 5];
    __shared__ int hist[G_];
    __shared__ int outf[G_];
    __shared__ double red[256];
    if (tid < G_ * 5) tr[tid] = targets[b * G_ * 5 + tid];
    if (tid < G_) {
        hist[tid] = 0;
        outf[tid] = (h->match_cnt[b * G_ + tid] < K_) ? 1 : 0;
    }
    __syncthreads();
    float4 pr = ((const float4*)priors)[p];
    float4 lc = ((const float4*)loc)[b * P_ + p];
    float bs = best_score[b * P_ + p];
    int bi = best_idx[b * P_ + p];
    float cmax = -INFINITY, mbest = -INFINITY;
    int mg = 0;
    for (int g = 0; g < G_; ++g) {
        float v = decoded_iou(pr, lc, tr[g * 5], tr[g * 5 + 1], tr[g * 5 + 2], tr[g * 5 + 3]);
        cmax = fmaxf(cmax, v);
        bool kill = outf[g] && (bi == g) && (bs > T1_);
        float v2 = kill ? 0.f : v;
        float m = outf[g] ? v2 : -1.f;
        if (m > mbest) { mbest = m; mg = g; }  // first-max
    }
    if (mbest > T2_) atomicAdd(&hist[mg], 1);
    bool n_pos = bs > T1_;
    bool ignore = (cmax > T2_) && (bs < T1_);
    bool neg = !(n_pos || ignore);
    double fl = 0.0;
    int lab = (int)tr[bi * 5 + 4];
    float2 cf = ((const float2*)conf)[b * (size_t)P_ + p];
    float cfs[2] = {cf.x, cf.y};
#pragma unroll
    for (int c = 0; c < C_; ++c) {
        if (n_pos) fl += (double)focal_f((c == lab) ? 1.f : 0.f, cfs[c], 1.f);
        else if (neg) fl += (double)focal_f(0.f, cfs[c], 1.f);
    }
    double sl = 0.0;
    if (n_pos) {
        float tx1 = tr[bi * 5], ty1 = tr[bi * 5 + 1], tx2 = tr[bi * 5 + 2], ty2 = tr[bi * 5 + 3];
        float e0 = ((tx1 + tx2) * 0.5f - pr.x) / (V0_ * pr.z);
        float e1 = ((ty1 + ty2) * 0.5f - pr.y) / (V0_ * pr.w);
        float e2 = logf((tx2 - tx1) / pr.z) / V1_;
        float e3 = logf((ty2 - ty1) / pr.w) / V1_;
        sl = (double)sml1(lc.x, e0) + (double)sml1(lc.y, e1) +
             (double)sml1(lc.z, e2) + (double)sml1(lc.w, e3);
    }
    red[tid] = fl;
    __syncthreads();
    for (int off = 128; off > 0; off >>= 1) {
        if (tid < off) red[tid] += red[tid + off];
        __syncthreads();
    }
    if (tid == 0) atomicAdd(&h->fl_n[b], red[0]);
    __syncthreads();
    red[tid] = sl;
    __syncthreads();
    for (int off = 128; off > 0; off >>= 1) {
        if (tid < off) red[tid] += red[tid + off];
        __syncthreads();
    }
    if (tid == 0) atomicAdd(&h->sl_n[b], red[0]);
    if (tid < G_ && hist[tid]) atomicAdd(&h->c_match[b * G_ + tid], hist[tid]);
}

// C: c_anchor_num, csum, npos
__global__ void kC(Hdr* h) {
    int i = threadIdx.x;  // 256 == B_*G_
    int b = i / G_;
    int mc = h->match_cnt[i];
    int cm = h->c_match[i];
    int n = (mc < K_) ? min(cm, K_ - mc) : 0;
    h->c_anchor_num[i] = n;
    atomicAdd(&h->csum[b], n);
    atomicAdd(&h->npos[b], mc);
}

// D: per-(b,g) exact top-5 of c_iou2 row (value desc, index asc), store n-th as cut
__global__ __launch_bounds__(256) void kD(const float* __restrict__ loc,
                                          const float* __restrict__ priors,
                                          const float* __restrict__ targets, Hdr* h,
                                          const float* __restrict__ best_score,
                                          const int* __restrict__ best_idx) {
    int g = blockIdx.x, b = blockIdx.y, tid = threadIdx.x;
    int n = h->c_anchor_num[b * G_ + g];
    if (n <= 0) return;  // uniform per block
    float tx1 = targets[(b * G_ + g) * 5 + 0], ty1 = targets[(b * G_ + g) * 5 + 1];
    float tx2 = targets[(b * G_ + g) * 5 + 2], ty2 = targets[(b * G_ + g) * 5 + 3];
    float lv[5];
    int li[5];
#pragma unroll
    for (int k = 0; k < 5; ++k) { lv[k] = -INFINITY; li[k] = 0x7fffffff; }
    for (int p = tid; p < P_; p += 256) {
        float4 pr = ((const float4*)priors)[p];
        float4 lc = ((const float4*)loc)[b * P_ + p];
        float v2;
        if (best_idx[b * P_ + p] == g && best_score[b * P_ + p] > T1_) v2 = 0.f;  // kill
        else v2 = decoded_iou(pr, lc, tx1, ty1, tx2, ty2);
        bool better = (v2 > lv[4]) || (v2 == lv[4] && p < li[4]);
        if (better) {
            lv[4] = v2; li[4] = p;
#pragma unroll
            for (int k = 4; k > 0; --k) {
                bool sw = (lv[k] > lv[k - 1]) || (lv[k] == lv[k - 1] && li[k] < li[k - 1]);
                if (sw) {
                    float tv = lv[k]; lv[k] = lv[k - 1]; lv[k - 1] = tv;
                    int ti = li[k]; li[k] = li[k - 1]; li[k - 1] = ti;
                }
            }
        }
    }
    __shared__ float sv[256 * 5];
    __shared__ int si[256 * 5];
#pragma unroll
    for (int k = 0; k < 5; ++k) { sv[tid * 5 + k] = lv[k]; si[tid * 5 + k] = li[k]; }
    __syncthreads();
    for (int str = 128; str > 0; str >>= 1) {
        if (tid < str) {
            int a = 0, c = 0;
            float ov[5];
            int oi[5];
#pragma unroll
            for (int k = 0; k < 5; ++k) {
                float va = sv[tid * 5 + a], vb = sv[(tid + str) * 5 + c];
                int ia = si[tid * 5 + a], ib = si[(tid + str) * 5 + c];
                bool ta = (va > vb) || (va == vb && ia < ib);
                ov[k] = ta ? va : vb;
                oi[k] = ta ? ia : ib;
                if (ta) a++; else c++;
            }
#pragma unroll
            for (int k = 0; k < 5; ++k) { sv[tid * 5 + k] = ov[k]; si[tid * 5 + k] = oi[k]; }
        }
        __syncthreads();
    }
    if (tid == 0) {
        h->cut_v[b * G_ + g] = sv[n - 1];
        h->cut_i[b * G_ + g] = si[n - 1];
    }
}

// E: apply selection (scan-override by ascending g), compensation losses
__global__ __launch_bounds__(256) void kE(const float* __restrict__ loc,
                                          const float* __restrict__ conf,
                                          const float* __restrict__ priors,
                                          const float* __restrict__ targets, Hdr* h,
                                          const float* __restrict__ best_score,
                                          const int* __restrict__ best_idx) {
    int tid = threadIdx.x;
    int p = blockIdx.x * 256 + tid, b = blockIdx.y;
    __shared__ float tr[G_ * 5];
    __shared__ int nsh[G_];
    __shared__ float cv[G_];
    __shared__ int ci[G_];
    __shared__ double red[256];
    if (tid < G_ * 5) tr[tid] = targets[b * G_ * 5 + tid];
    if (tid < G_) {
        nsh[tid] = h->c_anchor_num[b * G_ + tid];
        cv[tid] = h->cut_v[b * G_ + tid];
        ci[tid] = h->cut_i[b * G_ + tid];
    }
    __syncthreads();
    float4 pr = ((const float4*)priors)[p];
    float4 lc = ((const float4*)loc)[b * P_ + p];
    float bs = best_score[b * P_ + p];
    int bi = best_idx[b * P_ + p];
    int assign = -1;
    float comiou = 0.f;
    for (int g = 0; g < G_; ++g) {
        if (nsh[g] <= 0) continue;
        float v2;
        if (bi == g && bs > T1_) v2 = 0.f;  // kill (outface true since n>0)
        else v2 = decoded_iou(pr, lc, tr[g * 5], tr[g * 5 + 1], tr[g * 5 + 2], tr[g * 5 + 3]);
        bool sel = (v2 > cv[g]) || (v2 == cv[g] && p <= ci[g]);
        if (sel) { assign = g; comiou = v2; }  // later g overrides (scan order)
    }
    double slc = 0.0, flc = 0.0, cpos = 0.0;
    if (assign >= 0) {
        cpos = 1.0;
        float tx1 = tr[assign * 5], ty1 = tr[assign * 5 + 1];
        float tx2 = tr[assign * 5 + 2], ty2 = tr[assign * 5 + 3];
        float e0 = ((tx1 + tx2) * 0.5f - pr.x) / (V0_ * pr.z);
        float e1 = ((ty1 + ty2) * 0.5f - pr.y) / (V0_ * pr.w);
        float e2 = logf((tx2 - tx1) / pr.z) / V1_;
        float e3 = logf((ty2 - ty1) / pr.w) / V1_;
        slc = (double)sml1(lc.x, e0) + (double)sml1(lc.y, e1) +
              (double)sml1(lc.z, e2) + (double)sml1(lc.w, e3);
        float labf = tr[assign * 5 + 4];
        int labi = (int)labf;
        float2 cf = ((const float2*)conf)[b * (size_t)P_ + p];
        float cfs[2] = {cf.x, cf.y};
#pragma unroll
        for (int c = 0; c < C_; ++c) {
            float t = (c == labi) ? labf : 0.f;  // labels[g]*one_hot
            flc += (double)focal_f(t, cfs[c], comiou);
        }
    }
    red[tid] = slc;
    __syncthreads();
    for (int off = 128; off > 0; off >>= 1) {
        if (tid < off) red[tid] += red[tid + off];
        __syncthreads();
    }
    if (tid == 0) atomicAdd(&h->sl_c[b], red[0]);
    __syncthreads();
    red[tid] = flc;
    __syncthreads();
    for (int off = 128; off > 0; off >>= 1) {
        if (tid < off) red[tid] += red[tid + off];
        __syncthreads();
    }
    if (tid == 0) atomicAdd(&h->fl_c[b], red[0]);
    __syncthreads();
    red[tid] = cpos;
    __syncthreads();
    for (int off = 128; off > 0; off >>= 1) {
        if (tid < off) red[tid] += red[tid + off];
        __syncthreads();
    }
    if (tid == 0) atomicAdd(&h->npos_c[b], (int)red[0]);
}

// F: finalize means
__global__ void kF(Hdr* h, float* out) {
    if (threadIdx.x == 0) {
        double sll = 0.0, scl = 0.0;
        for (int b = 0; b < B_; ++b) {
            double l_loc = 0.0, l_cls = 0.0;
            int npos = h->npos[b];
            if (npos > 0) {
                double nf = (double)npos;
                l_cls += h->fl_n[b] / nf;
                l_loc += h->sl_n[b] / nf;
            }
            int csum = h->csum[b];
            if (csum > 0) {
                double npc = (double)((h->npos_c[b] > 1) ? h->npos_c[b] : 1);
                l_loc += h->sl_c[b] / npc;
                l_cls += h->fl_c[b] / (double)csum;
            }
            sll += l_loc;
            scl += l_cls;
        }
        out[0] = (float)(sll / B_);
        out[1] = (float)(scl / B_);
    }
}

extern "C" void kernel_launch(void* const* d_in, const int* in_sizes, int n_in,
                              void* d_out, int out_size, void* d_ws, size_t ws_size,
                              hipStream_t stream) {
    (void)in_sizes; (void)n_in; (void)out_size; (void)ws_size;
    const float* loc = (const float*)d_in[0];
    const float* conf = (const float*)d_in[1];
    const float* priors = (const float*)d_in[2];
    const float* targets = (const float*)d_in[3];
    float* out = (float*)d_out;
    char* ws = (char*)d_ws;
    Hdr* h = (Hdr*)ws;
    float* best_score = (float*)(ws + 8192);
    int* best_idx = (int*)(ws + 8192 + (size_t)B_ * P_ * 4);

    dim3 gridP(P_ / 256, B_);
    kInit<<<1, 256, 0, stream>>>((int*)ws);
    kA<<<gridP, 256, 0, stream>>>(priors, targets, h, best_score, best_idx);
    kB<<<gridP, 256, 0, stream>>>(loc, conf, priors, targets, h, best_score, best_idx);
    kC<<<1, 256, 0, stream>>>(h);
    kD<<<dim3(G_, B_), 256, 0, stream>>>(loc, priors, targets, h, best_score, best_idx);
    kE<<<gridP, 256, 0, stream>>>(loc, conf, priors, targets, h, best_score, best_idx);
    kF<<<1, 64, 0, stream>>>(h, out);
}

// Round 3
// 81.144 us; speedup vs baseline: 1.4156x; 1.4156x over previous
//
#include <hip/hip_runtime.h>

#define B_ 8
#define P_ 65536
#define G_ 32
#define C_ 2
#define K_ 5
#define T1_ 0.35f
#define T2_ 0.5f
#define ALPHA_ 0.25f
#define BETA_ 0.11f
#define V0_ 0.1f
#define V1_ 0.2f

#define NBLK_ (P_ / 256)           // 256 blocks per image
#define NPART_ (B_ * NBLK_)        // 2048 partial slots

// ---------------- workspace header (first 8192 bytes of d_ws, zeroed each call) ----
struct Hdr {
    int npos[B_], npos_c[B_], csum[B_];
    int match_cnt[B_ * G_], c_match[B_ * G_], c_anchor_num[B_ * G_];
    float cut_v[B_ * G_];
    int cut_i[B_ * G_];
};
// ws layout after 8192B header:
//   float best_score[B_*P_]            (2 MB)
//   int   best_idx[B_*P_]              (2 MB)
//   double parts[4][NPART_]            (64 KB)  order: fl_n, sl_n, fl_c, sl_c

// ---------------- helpers ----------------
__device__ __forceinline__ float iou_corner(float ax1, float ay1, float ax2, float ay2,
                                            float bx1, float by1, float bx2, float by2) {
    float lx = fmaxf(ax1, bx1), ly = fmaxf(ay1, by1);
    float rx = fminf(ax2, bx2), ry = fminf(ay2, by2);
    float w = fmaxf(rx - lx, 0.f), hh = fmaxf(ry - ly, 0.f);
    float inter = w * hh;
    float aa = (ax2 - ax1) * (ay2 - ay1);
    float ab = (bx2 - bx1) * (by2 - by1);
    return inter / (aa + ab - inter);
}

// decode(loc,prior) then IoU vs a gt box. contract(off) so kernels D and E
// produce BIT-IDENTICAL values (the stable-sort tie-break compares floats for
// equality across kernels).
__device__ __forceinline__ float decoded_iou(float4 pr, float4 lc,
                                             float tx1, float ty1, float tx2, float ty2) {
#pragma clang fp contract(off)
    float dcx = pr.x + lc.x * V0_ * pr.z;
    float dcy = pr.y + lc.y * V0_ * pr.w;
    float dw = pr.z * expf(lc.z * V1_);
    float dh = pr.w * expf(lc.w * V1_);
    float dx1 = dcx - dw * 0.5f, dy1 = dcy - dh * 0.5f;
    float dx2 = dcx + dw * 0.5f, dy2 = dcy + dh * 0.5f;
    float lx = fmaxf(tx1, dx1), ly = fmaxf(ty1, dy1);
    float rx = fminf(tx2, dx2), ry = fminf(ty2, dy2);
    float w = fmaxf(rx - lx, 0.f), hh = fmaxf(ry - ly, 0.f);
    float inter = w * hh;
    float aa = (tx2 - tx1) * (ty2 - ty1);
    float ab = (dx2 - dx1) * (dy2 - dy1);
    return inter / (aa + ab - inter);
}

__device__ __forceinline__ float focal_f(float t, float x, float fiou) {
    float ce = fmaxf(x, 0.f) - x * t + log1pf(expf(-fabsf(x)));
    float a = (t * ALPHA_ + (1.f - t) * (1.f - ALPHA_)) * fiou;
    float pt = (t == 1.0f) ? x : 1.f - x;
    float om = 1.f - pt;
    return a * om * om * ce;  // GAMMA = 2
}

__device__ __forceinline__ float sml1(float p, float t) {
    float x = fabsf(p - t);
    return (x >= BETA_) ? (x - 0.5f * BETA_) : (0.5f * x * x / BETA_);
}

// ---------------- kernels ----------------
__global__ void kInit(int* hw) {
    for (int k = threadIdx.x; k < 2048; k += 256) hw[k] = 0;  // zero first 8192 B
}

// A: prior<->gt IoU, best match per anchor, match_cnt histogram
__global__ __launch_bounds__(256) void kA(const float* __restrict__ priors,
                                          const float* __restrict__ targets, Hdr* h,
                                          float* __restrict__ best_score,
                                          int* __restrict__ best_idx) {
    int tid = threadIdx.x;
    int p = blockIdx.x * 256 + tid, b = blockIdx.y;
    __shared__ float tr[G_ * 5];
    __shared__ int hist[G_];
    if (tid < G_ * 5) tr[tid] = targets[b * G_ * 5 + tid];
    if (tid < G_) hist[tid] = 0;
    __syncthreads();
    float4 pr = ((const float4*)priors)[p];
    float px1 = pr.x - pr.z * 0.5f, py1 = pr.y - pr.w * 0.5f;
    float px2 = pr.x + pr.z * 0.5f, py2 = pr.y + pr.w * 0.5f;
    float best = -INFINITY;
    int bi = 0;
    for (int g = 0; g < G_; ++g) {
        float v = iou_corner(tr[g * 5], tr[g * 5 + 1], tr[g * 5 + 2], tr[g * 5 + 3],
                             px1, py1, px2, py2);
        if (v > best) { best = v; bi = g; }  // first-max == jnp.argmax
    }
    best_score[b * P_ + p] = best;
    best_idx[b * P_ + p] = bi;
    if (best > T1_) atomicAdd(&hist[bi], 1);
    __syncthreads();
    if (tid < G_ && hist[tid]) atomicAdd(&h->match_cnt[b * G_ + tid], hist[tid]);
}

// B: decode, c_iou over g, ignore/neg masks, normal focal+smoothL1, c_match.
// Block sums go to per-block partial slots (NO fp atomics -> no CAS storms).
__global__ __launch_bounds__(256) void kB(const float* __restrict__ loc,
                                          const float* __restrict__ conf,
                                          const float* __restrict__ priors,
                                          const float* __restrict__ targets, Hdr* h,
                                          const float* __restrict__ best_score,
                                          const int* __restrict__ best_idx,
                                          double* __restrict__ fl_n_p,
                                          double* __restrict__ sl_n_p) {
    int tid = threadIdx.x;
    int p = blockIdx.x * 256 + tid, b = blockIdx.y;
    __shared__ float tr[G_ * 5];
    __shared__ int hist[G_];
    __shared__ int outf[G_];
    __shared__ double redA[256], redB[256];
    if (tid < G_ * 5) tr[tid] = targets[b * G_ * 5 + tid];
    if (tid < G_) {
        hist[tid] = 0;
        outf[tid] = (h->match_cnt[b * G_ + tid] < K_) ? 1 : 0;
    }
    __syncthreads();
    float4 pr = ((const float4*)priors)[p];
    float4 lc = ((const float4*)loc)[b * P_ + p];
    float bs = best_score[b * P_ + p];
    int bi = best_idx[b * P_ + p];
    float cmax = -INFINITY, mbest = -INFINITY;
    int mg = 0;
    for (int g = 0; g < G_; ++g) {
        float v = decoded_iou(pr, lc, tr[g * 5], tr[g * 5 + 1], tr[g * 5 + 2], tr[g * 5 + 3]);
        cmax = fmaxf(cmax, v);
        bool kill = outf[g] && (bi == g) && (bs > T1_);
        float v2 = kill ? 0.f : v;
        float m = outf[g] ? v2 : -1.f;
        if (m > mbest) { mbest = m; mg = g; }  // first-max
    }
    if (mbest > T2_) atomicAdd(&hist[mg], 1);
    bool n_pos = bs > T1_;
    bool ignore = (cmax > T2_) && (bs < T1_);
    bool neg = !(n_pos || ignore);
    double fl = 0.0;
    int lab = (int)tr[bi * 5 + 4];
    float2 cf = ((const float2*)conf)[b * (size_t)P_ + p];
    float cfs[2] = {cf.x, cf.y};
#pragma unroll
    for (int c = 0; c < C_; ++c) {
        if (n_pos) fl += (double)focal_f((c == lab) ? 1.f : 0.f, cfs[c], 1.f);
        else if (neg) fl += (double)focal_f(0.f, cfs[c], 1.f);
    }
    double sl = 0.0;
    if (n_pos) {
        float tx1 = tr[bi * 5], ty1 = tr[bi * 5 + 1], tx2 = tr[bi * 5 + 2], ty2 = tr[bi * 5 + 3];
        float e0 = ((tx1 + tx2) * 0.5f - pr.x) / (V0_ * pr.z);
        float e1 = ((ty1 + ty2) * 0.5f - pr.y) / (V0_ * pr.w);
        float e2 = logf((tx2 - tx1) / pr.z) / V1_;
        float e3 = logf((ty2 - ty1) / pr.w) / V1_;
        sl = (double)sml1(lc.x, e0) + (double)sml1(lc.y, e1) +
             (double)sml1(lc.z, e2) + (double)sml1(lc.w, e3);
    }
    redA[tid] = fl;
    redB[tid] = sl;
    __syncthreads();
    for (int off = 128; off > 0; off >>= 1) {
        if (tid < off) { redA[tid] += redA[tid + off]; redB[tid] += redB[tid + off]; }
        __syncthreads();
    }
    if (tid == 0) {
        fl_n_p[b * NBLK_ + blockIdx.x] = redA[0];
        sl_n_p[b * NBLK_ + blockIdx.x] = redB[0];
    }
    if (tid < G_ && hist[tid]) atomicAdd(&h->c_match[b * G_ + tid], hist[tid]);
}

// C: c_anchor_num, csum, npos
__global__ void kC(Hdr* h) {
    int i = threadIdx.x;  // 256 == B_*G_
    int b = i / G_;
    int mc = h->match_cnt[i];
    int cm = h->c_match[i];
    int n = (mc < K_) ? min(cm, K_ - mc) : 0;
    h->c_anchor_num[i] = n;
    atomicAdd(&h->csum[b], n);
    atomicAdd(&h->npos[b], mc);
}

// D: per-(b,g) exact top-5 of c_iou2 row (value desc, index asc), store n-th as cut
__global__ __launch_bounds__(256) void kD(const float* __restrict__ loc,
                                          const float* __restrict__ priors,
                                          const float* __restrict__ targets, Hdr* h,
                                          const float* __restrict__ best_score,
                                          const int* __restrict__ best_idx) {
    int g = blockIdx.x, b = blockIdx.y, tid = threadIdx.x;
    int n = h->c_anchor_num[b * G_ + g];
    if (n <= 0) return;  // uniform per block
    float tx1 = targets[(b * G_ + g) * 5 + 0], ty1 = targets[(b * G_ + g) * 5 + 1];
    float tx2 = targets[(b * G_ + g) * 5 + 2], ty2 = targets[(b * G_ + g) * 5 + 3];
    float lv[5];
    int li[5];
#pragma unroll
    for (int k = 0; k < 5; ++k) { lv[k] = -INFINITY; li[k] = 0x7fffffff; }
    for (int p = tid; p < P_; p += 256) {
        float4 pr = ((const float4*)priors)[p];
        float4 lc = ((const float4*)loc)[b * P_ + p];
        float v2;
        if (best_idx[b * P_ + p] == g && best_score[b * P_ + p] > T1_) v2 = 0.f;  // kill
        else v2 = decoded_iou(pr, lc, tx1, ty1, tx2, ty2);
        bool better = (v2 > lv[4]) || (v2 == lv[4] && p < li[4]);
        if (better) {
            lv[4] = v2; li[4] = p;
#pragma unroll
            for (int k = 4; k > 0; --k) {
                bool sw = (lv[k] > lv[k - 1]) || (lv[k] == lv[k - 1] && li[k] < li[k - 1]);
                if (sw) {
                    float tv = lv[k]; lv[k] = lv[k - 1]; lv[k - 1] = tv;
                    int ti = li[k]; li[k] = li[k - 1]; li[k - 1] = ti;
                }
            }
        }
    }
    __shared__ float sv[256 * 5];
    __shared__ int si[256 * 5];
#pragma unroll
    for (int k = 0; k < 5; ++k) { sv[tid * 5 + k] = lv[k]; si[tid * 5 + k] = li[k]; }
    __syncthreads();
    for (int str = 128; str > 0; str >>= 1) {
        if (tid < str) {
            int a = 0, c = 0;
            float ov[5];
            int oi[5];
#pragma unroll
            for (int k = 0; k < 5; ++k) {
                float va = sv[tid * 5 + a], vb = sv[(tid + str) * 5 + c];
                int ia = si[tid * 5 + a], ib = si[(tid + str) * 5 + c];
                bool ta = (va > vb) || (va == vb && ia < ib);
                ov[k] = ta ? va : vb;
                oi[k] = ta ? ia : ib;
                if (ta) a++; else c++;
            }
#pragma unroll
            for (int k = 0; k < 5; ++k) { sv[tid * 5 + k] = ov[k]; si[tid * 5 + k] = oi[k]; }
        }
        __syncthreads();
    }
    if (tid == 0) {
        h->cut_v[b * G_ + g] = sv[n - 1];
        h->cut_i[b * G_ + g] = si[n - 1];
    }
}

// E: apply selection (scan-override by ascending g), compensation losses.
// Block sums -> partial slots; npos_c via per-wave ballot + native int atomic.
__global__ __launch_bounds__(256) void kE(const float* __restrict__ loc,
                                          const float* __restrict__ conf,
                                          const float* __restrict__ priors,
                                          const float* __restrict__ targets, Hdr* h,
                                          const float* __restrict__ best_score,
                                          const int* __restrict__ best_idx,
                                          double* __restrict__ fl_c_p,
                                          double* __restrict__ sl_c_p) {
    int tid = threadIdx.x;
    int p = blockIdx.x * 256 + tid, b = blockIdx.y;
    __shared__ float tr[G_ * 5];
    __shared__ int nsh[G_];
    __shared__ float cv[G_];
    __shared__ int ci[G_];
    __shared__ double redA[256], redB[256];
    if (tid < G_ * 5) tr[tid] = targets[b * G_ * 5 + tid];
    if (tid < G_) {
        nsh[tid] = h->c_anchor_num[b * G_ + tid];
        cv[tid] = h->cut_v[b * G_ + tid];
        ci[tid] = h->cut_i[b * G_ + tid];
    }
    __syncthreads();
    float4 pr = ((const float4*)priors)[p];
    float4 lc = ((const float4*)loc)[b * P_ + p];
    float bs = best_score[b * P_ + p];
    int bi = best_idx[b * P_ + p];
    int assign = -1;
    float comiou = 0.f;
    for (int g = 0; g < G_; ++g) {
        if (nsh[g] <= 0) continue;
        float v2;
        if (bi == g && bs > T1_) v2 = 0.f;  // kill (outface true since n>0)
        else v2 = decoded_iou(pr, lc, tr[g * 5], tr[g * 5 + 1], tr[g * 5 + 2], tr[g * 5 + 3]);
        bool sel = (v2 > cv[g]) || (v2 == cv[g] && p <= ci[g]);
        if (sel) { assign = g; comiou = v2; }  // later g overrides (scan order)
    }
    double slc = 0.0, flc = 0.0;
    if (assign >= 0) {
        float tx1 = tr[assign * 5], ty1 = tr[assign * 5 + 1];
        float tx2 = tr[assign * 5 + 2], ty2 = tr[assign * 5 + 3];
        float e0 = ((tx1 + tx2) * 0.5f - pr.x) / (V0_ * pr.z);
        float e1 = ((ty1 + ty2) * 0.5f - pr.y) / (V0_ * pr.w);
        float e2 = logf((tx2 - tx1) / pr.z) / V1_;
        float e3 = logf((ty2 - ty1) / pr.w) / V1_;
        slc = (double)sml1(lc.x, e0) + (double)sml1(lc.y, e1) +
              (double)sml1(lc.z, e2) + (double)sml1(lc.w, e3);
        float labf = tr[assign * 5 + 4];
        int labi = (int)labf;
        float2 cf = ((const float2*)conf)[b * (size_t)P_ + p];
        float cfs[2] = {cf.x, cf.y};
#pragma unroll
        for (int c = 0; c < C_; ++c) {
            float t = (c == labi) ? labf : 0.f;  // labels[g]*one_hot
            flc += (double)focal_f(t, cfs[c], comiou);
        }
    }
    // npos_c: per-wave ballot + native int32 atomic (no CAS)
    unsigned long long bal = __ballot(assign >= 0);
    if ((tid & 63) == 0) {
        int cnt = __popcll(bal);
        if (cnt) atomicAdd(&h->npos_c[b], cnt);
    }
    redA[tid] = slc;
    redB[tid] = flc;
    __syncthreads();
    for (int off = 128; off > 0; off >>= 1) {
        if (tid < off) { redA[tid] += redA[tid + off]; redB[tid] += redB[tid + off]; }
        __syncthreads();
    }
    if (tid == 0) {
        sl_c_p[b * NBLK_ + blockIdx.x] = redA[0];
        fl_c_p[b * NBLK_ + blockIdx.x] = redB[0];
    }
}

// F: reduce per-block partials (4 waves, one quantity each) + finalize means
__global__ __launch_bounds__(256) void kF(Hdr* h, const double* __restrict__ parts,
                                          float* __restrict__ out) {
    __shared__ double acc[4][B_];
    int tid = threadIdx.x;
    int w = tid >> 6, lane = tid & 63;
    const double* src = parts + (size_t)w * NPART_;  // 0=fl_n 1=sl_n 2=fl_c 3=sl_c
    for (int b = 0; b < B_; ++b) {
        double s = 0.0;
        for (int k = lane; k < NBLK_; k += 64) s += src[b * NBLK_ + k];
        for (int off = 32; off > 0; off >>= 1) s += __shfl_down(s, off, 64);
        if (lane == 0) acc[w][b] = s;
    }
    __syncthreads();
    if (tid == 0) {
        double sll = 0.0, scl = 0.0;
        for (int b = 0; b < B_; ++b) {
            double l_loc = 0.0, l_cls = 0.0;
            int npos = h->npos[b];
            if (npos > 0) {
                double nf = (double)npos;
                l_cls += acc[0][b] / nf;
                l_loc += acc[1][b] / nf;
            }
            int csum = h->csum[b];
            if (csum > 0) {
                double npc = (double)((h->npos_c[b] > 1) ? h->npos_c[b] : 1);
                l_loc += acc[3][b] / npc;
                l_cls += acc[2][b] / (double)csum;
            }
            sll += l_loc;
            scl += l_cls;
        }
        out[0] = (float)(sll / B_);
        out[1] = (float)(scl / B_);
    }
}

extern "C" void kernel_launch(void* const* d_in, const int* in_sizes, int n_in,
                              void* d_out, int out_size, void* d_ws, size_t ws_size,
                              hipStream_t stream) {
    (void)in_sizes; (void)n_in; (void)out_size; (void)ws_size;
    const float* loc = (const float*)d_in[0];
    const float* conf = (const float*)d_in[1];
    const float* priors = (const float*)d_in[2];
    const float* targets = (const float*)d_in[3];
    float* out = (float*)d_out;
    char* ws = (char*)d_ws;
    Hdr* h = (Hdr*)ws;
    float* best_score = (float*)(ws + 8192);
    int* best_idx = (int*)(ws + 8192 + (size_t)B_ * P_ * 4);
    double* parts = (double*)(ws + 8192 + (size_t)B_ * P_ * 8);  // 4 arrays of NPART_
    double* fl_n_p = parts + 0 * NPART_;
    double* sl_n_p = parts + 1 * NPART_;
    double* fl_c_p = parts + 2 * NPART_;
    double* sl_c_p = parts + 3 * NPART_;

    dim3 gridP(NBLK_, B_);
    kInit<<<1, 256, 0, stream>>>((int*)ws);
    kA<<<gridP, 256, 0, stream>>>(priors, targets, h, best_score, best_idx);
    kB<<<gridP, 256, 0, stream>>>(loc, conf, priors, targets, h, best_score, best_idx,
                                  fl_n_p, sl_n_p);
    kC<<<1, 256, 0, stream>>>(h);
    kD<<<dim3(G_, B_), 256, 0, stream>>>(loc, priors, targets, h, best_score, best_idx);
    kE<<<gridP, 256, 0, stream>>>(loc, conf, priors, targets, h, best_score, best_idx,
                                  fl_c_p, sl_c_p);
    kF<<<1, 256, 0, stream>>>(h, parts, out);
}